// Round 2
// baseline (1647.493 us; speedup 1.0000x reference)
//
#include <hip/hip_runtime.h>

#define D 512
#define T 2048
#define BATCH 8
#define M_ROWS (BATCH*T)   // 16384

typedef __attribute__((ext_vector_type(8))) short short8;
typedef __attribute__((ext_vector_type(4))) float floatx4;

__device__ __forceinline__ unsigned short f2bf(float f) {
  unsigned int u = __float_as_uint(f);
  u += 0x7FFFu + ((u >> 16) & 1u);          // round-to-nearest-even
  return (unsigned short)(u >> 16);
}
__device__ __forceinline__ float bf2f(unsigned int h) {
  return __uint_as_float(h << 16);
}
__device__ __forceinline__ void unpack8(uint4 r, float f[8]) {
  f[0] = bf2f(r.x & 0xffffu); f[1] = bf2f(r.x >> 16);
  f[2] = bf2f(r.y & 0xffffu); f[3] = bf2f(r.y >> 16);
  f[4] = bf2f(r.z & 0xffffu); f[5] = bf2f(r.z >> 16);
  f[6] = bf2f(r.w & 0xffffu); f[7] = bf2f(r.w >> 16);
}
__device__ __forceinline__ float wave_allreduce(float v) {
  #pragma unroll
  for (int m = 32; m; m >>= 1) v += __shfl_xor(v, m, 64);
  return v;
}

// ---------------- f32 -> bf16 cast (8 elems/thread) ----------------
__global__ __launch_bounds__(256) void cast_kernel(const float* __restrict__ src,
                                                   unsigned short* __restrict__ dst, int n) {
  int idx = (blockIdx.x * 256 + threadIdx.x) * 8;
  if (idx >= n) return;
  const float4* sp = (const float4*)(src + idx);
  float4 a = sp[0], b = sp[1];
  uint4 o;
  o.x = f2bf(a.x) | ((unsigned)f2bf(a.y) << 16);
  o.y = f2bf(a.z) | ((unsigned)f2bf(a.w) << 16);
  o.z = f2bf(b.x) | ((unsigned)f2bf(b.y) << 16);
  o.w = f2bf(b.z) | ((unsigned)f2bf(b.w) << 16);
  *(uint4*)(dst + idx) = o;
}

// ---------------- bf16 MFMA GEMM: C = A(MxK) * W(NxK)^T + bias ----------------
// 128x128 block tile, 4 waves in 2x2, each wave 64x64 via 4x4 MFMA 16x16x32 tiles.
#define BM 128
#define BN 128
#define BK 32

template<bool OUT_BF16>
__global__ __launch_bounds__(256) void gemm_nt(
    const unsigned short* __restrict__ A, const unsigned short* __restrict__ Bw,
    const float* __restrict__ bias, void* __restrict__ Cout, int M, int N, int K)
{
  __shared__ unsigned short As[BM * BK];
  __shared__ unsigned short Bs[BN * BK];
  int tid  = threadIdx.x;
  int lane = tid & 63;
  int wave = tid >> 6;
  int waveM = (wave >> 1) * 64;
  int waveN = (wave & 1) * 64;
  int lrow = lane & 15;           // A-row / B-row(=C col) within 16-tile
  int quad = lane >> 4;           // k-quad: k = quad*8 + j

  floatx4 acc[4][4];
  #pragma unroll
  for (int a_ = 0; a_ < 4; ++a_)
    #pragma unroll
    for (int b_ = 0; b_ < 4; ++b_) acc[a_][b_] = (floatx4){0.f, 0.f, 0.f, 0.f};

  const unsigned short* Ap = A  + (size_t)(blockIdx.y * BM) * K;
  const unsigned short* Bp = Bw + (size_t)(blockIdx.x * BN) * K;
  // staging: 512 uint4 per buffer (BM*BK shorts); thread covers u = tid and tid+256
  int r0 = tid >> 2;              // row 0..63
  int c0 = (tid & 3) * 8;         // short offset 0,8,16,24

  for (int k0 = 0; k0 < K; k0 += BK) {
    __syncthreads();
    *(uint4*)&As[r0 * BK + c0]        = *(const uint4*)&Ap[(size_t)r0 * K + k0 + c0];
    *(uint4*)&As[(r0 + 64) * BK + c0] = *(const uint4*)&Ap[(size_t)(r0 + 64) * K + k0 + c0];
    *(uint4*)&Bs[r0 * BK + c0]        = *(const uint4*)&Bp[(size_t)r0 * K + k0 + c0];
    *(uint4*)&Bs[(r0 + 64) * BK + c0] = *(const uint4*)&Bp[(size_t)(r0 + 64) * K + k0 + c0];
    __syncthreads();
    short8 af[4], bf[4];
    #pragma unroll
    for (int mt = 0; mt < 4; ++mt)
      af[mt] = *(const short8*)&As[(waveM + mt * 16 + lrow) * BK + quad * 8];
    #pragma unroll
    for (int nt = 0; nt < 4; ++nt)
      bf[nt] = *(const short8*)&Bs[(waveN + nt * 16 + lrow) * BK + quad * 8];
    #pragma unroll
    for (int mt = 0; mt < 4; ++mt)
      #pragma unroll
      for (int nt = 0; nt < 4; ++nt)
        acc[mt][nt] = __builtin_amdgcn_mfma_f32_16x16x32_bf16(af[mt], bf[nt], acc[mt][nt], 0, 0, 0);
  }

  int cm = blockIdx.y * BM + waveM;
  int cn = blockIdx.x * BN + waveN;
  #pragma unroll
  for (int nt = 0; nt < 4; ++nt) {
    int col = cn + nt * 16 + lrow;          // C/D: col = lane&15
    float bv = bias[col];
    #pragma unroll
    for (int mt = 0; mt < 4; ++mt) {
      #pragma unroll
      for (int r = 0; r < 4; ++r) {
        int row = cm + mt * 16 + quad * 4 + r;   // C/D: row = (lane>>4)*4 + reg
        float v = acc[mt][nt][r] + bv;
        if (OUT_BF16) ((unsigned short*)Cout)[(size_t)row * N + col] = f2bf(v);
        else          ((float*)Cout)[(size_t)row * N + col] = v;
      }
    }
  }
}

// ---------------- K l2-normalize (in place, bf16) + Beta = sigmoid(Kn.Wbeta + bbeta) ----------------
__global__ __launch_bounds__(256) void norm_beta_kernel(
    unsigned short* __restrict__ Kb, const float* __restrict__ Wbeta,
    const float* __restrict__ bbeta, float* __restrict__ Beta)
{
  int w = blockIdx.x * 4 + (threadIdx.x >> 6);   // row 0..16383
  int lane = threadIdx.x & 63;
  unsigned short* kp = Kb + (size_t)w * D + lane * 8;
  uint4 raw = *(uint4*)kp;
  float kv[8]; unpack8(raw, kv);
  float ss = 0.f;
  #pragma unroll
  for (int m = 0; m < 8; ++m) ss += kv[m] * kv[m];
  ss = wave_allreduce(ss);
  float inv = 1.0f / fmaxf(sqrtf(ss), 1e-12f);
  const float* wb = Wbeta + lane * 8;
  float dotp = 0.f;
  #pragma unroll
  for (int m = 0; m < 8; ++m) { kv[m] *= inv; dotp += kv[m] * wb[m]; }
  uint4 o;
  o.x = f2bf(kv[0]) | ((unsigned)f2bf(kv[1]) << 16);
  o.y = f2bf(kv[2]) | ((unsigned)f2bf(kv[3]) << 16);
  o.z = f2bf(kv[4]) | ((unsigned)f2bf(kv[5]) << 16);
  o.w = f2bf(kv[6]) | ((unsigned)f2bf(kv[7]) << 16);
  *(uint4*)kp = o;
  dotp = wave_allreduce(dotp);
  if (lane == 0) Beta[w] = 1.0f / (1.0f + expf(-(dotp + bbeta[0])));
}

// ---------------- DeltaNet scan: one wave per (batch, state-row) ----------------
// S[i,:] held in 8 f32/lane. Per step: Sk = S[i,:].k (all-reduce), S[i,:] += beta*(v_i-Sk)*k,
// o_i = S[i,:].q (all-reduce). State never leaves registers.
__global__ __launch_bounds__(256) void scan_kernel(
    const unsigned short* __restrict__ Qb, const unsigned short* __restrict__ Kb,
    const unsigned short* __restrict__ Vb, const float* __restrict__ Beta,
    unsigned short* __restrict__ Ob)
{
  int w = blockIdx.x * 4 + (threadIdx.x >> 6);   // 0..4095
  int lane = threadIdx.x & 63;
  int b = w >> 9;          // batch 0..7
  int i = w & 511;         // state row
  int base = b * (T * D);
  int ro = lane * 8;
  float s[8] = {0.f,0.f,0.f,0.f,0.f,0.f,0.f,0.f};

  uint4 kr = *(const uint4*)&Kb[base + ro];
  uint4 qr = *(const uint4*)&Qb[base + ro];
  float beta = Beta[b * T];
  float vi = bf2f(Vb[base + i]);

  for (int t = 0; t < T; ++t) {
    int tn = (t + 1 < T) ? (t + 1) : t;
    int noff = base + tn * D;
    uint4 krn = *(const uint4*)&Kb[noff + ro];     // prefetch next step
    uint4 qrn = *(const uint4*)&Qb[noff + ro];
    float betan = Beta[b * T + tn];
    float vin = bf2f(Vb[noff + i]);

    float kf[8], qf[8];
    unpack8(kr, kf); unpack8(qr, qf);
    float skp = 0.f;
    #pragma unroll
    for (int m = 0; m < 8; ++m) skp += s[m] * kf[m];
    float Sk = wave_allreduce(skp);
    float c = beta * (vi - Sk);
    float op = 0.f;
    #pragma unroll
    for (int m = 0; m < 8; ++m) { s[m] += c * kf[m]; op += s[m] * qf[m]; }
    float o = wave_allreduce(op);
    if (lane == 0) Ob[base + t * D + i] = f2bf(o);

    kr = krn; qr = qrn; beta = betan; vi = vin;
  }
}

extern "C" void kernel_launch(void* const* d_in, const int* in_sizes, int n_in,
                              void* d_out, int out_size, void* d_ws, size_t ws_size,
                              hipStream_t stream) {
  const float* x     = (const float*)d_in[0];
  const float* Wq    = (const float*)d_in[1];
  const float* bq    = (const float*)d_in[2];
  const float* Wk    = (const float*)d_in[3];
  const float* bk    = (const float*)d_in[4];
  const float* Wv    = (const float*)d_in[5];
  const float* bv    = (const float*)d_in[6];
  const float* Wbeta = (const float*)d_in[7];
  const float* bbeta = (const float*)d_in[8];
  const float* Wo    = (const float*)d_in[9];
  const float* bo    = (const float*)d_in[10];

  const size_t NE = (size_t)M_ROWS * D;            // 8,388,608 elems
  unsigned short* Qb  = (unsigned short*)d_ws;     // bf16, NE each
  unsigned short* Kb  = Qb + NE;
  unsigned short* Vb  = Kb + NE;
  unsigned short* Xb  = Vb + NE;                   // x bf16; reused as pre-Wo output
  unsigned short* Wqb = Xb + NE;
  unsigned short* Wkb = Wqb + D * D;
  unsigned short* Wvb = Wkb + D * D;
  unsigned short* Wob = Wvb + D * D;
  float* Beta = (float*)(Wob + D * D);             // 16384 f32; total ws ~66 MB

  cast_kernel<<<(int)(NE / 2048), 256, 0, stream>>>(x, Xb, (int)NE);
  cast_kernel<<<(D * D) / 2048, 256, 0, stream>>>(Wq, Wqb, D * D);
  cast_kernel<<<(D * D) / 2048, 256, 0, stream>>>(Wk, Wkb, D * D);
  cast_kernel<<<(D * D) / 2048, 256, 0, stream>>>(Wv, Wvb, D * D);
  cast_kernel<<<(D * D) / 2048, 256, 0, stream>>>(Wo, Wob, D * D);

  dim3 gg(D / BN, M_ROWS / BM);  // (4, 128)
  gemm_nt<true><<<gg, 256, 0, stream>>>(Xb, Wqb, bq, Qb, M_ROWS, D, D);
  gemm_nt<true><<<gg, 256, 0, stream>>>(Xb, Wkb, bk, Kb, M_ROWS, D, D);
  gemm_nt<true><<<gg, 256, 0, stream>>>(Xb, Wvb, bv, Vb, M_ROWS, D, D);

  norm_beta_kernel<<<M_ROWS / 4, 256, 0, stream>>>(Kb, Wbeta, bbeta, Beta);

  scan_kernel<<<(BATCH * D) / 4, 256, 0, stream>>>(Qb, Kb, Vb, Beta, Xb);

  gemm_nt<false><<<gg, 256, 0, stream>>>(Xb, Wob, bo, (float*)d_out, M_ROWS, D, D);
}

// Round 3
// 1325.667 us; speedup vs baseline: 1.2428x; 1.2428x over previous
//
#include <hip/hip_runtime.h>

#define D 512
#define T 2048
#define BATCH 8
#define M_ROWS (BATCH*T)   // 16384

typedef __attribute__((ext_vector_type(8))) short short8;
typedef __attribute__((ext_vector_type(4))) float floatx4;

__device__ __forceinline__ unsigned short f2bf(float f) {
  unsigned int u = __float_as_uint(f);
  u += 0x7FFFu + ((u >> 16) & 1u);          // round-to-nearest-even
  return (unsigned short)(u >> 16);
}
__device__ __forceinline__ float bf2f(unsigned int h) {
  return __uint_as_float(h << 16);
}
__device__ __forceinline__ void unpack8(uint4 r, float f[8]) {
  f[0] = bf2f(r.x & 0xffffu); f[1] = bf2f(r.x >> 16);
  f[2] = bf2f(r.y & 0xffffu); f[3] = bf2f(r.y >> 16);
  f[4] = bf2f(r.z & 0xffffu); f[5] = bf2f(r.z >> 16);
  f[6] = bf2f(r.w & 0xffffu); f[7] = bf2f(r.w >> 16);
}
__device__ __forceinline__ float wave_allreduce(float v) {
  #pragma unroll
  for (int m = 32; m; m >>= 1) v += __shfl_xor(v, m, 64);
  return v;
}

// ---------------- f32 -> bf16 cast (8 elems/thread) ----------------
__global__ __launch_bounds__(256) void cast_kernel(const float* __restrict__ src,
                                                   unsigned short* __restrict__ dst, int n) {
  int idx = (blockIdx.x * 256 + threadIdx.x) * 8;
  if (idx >= n) return;
  const float4* sp = (const float4*)(src + idx);
  float4 a = sp[0], b = sp[1];
  uint4 o;
  o.x = f2bf(a.x) | ((unsigned)f2bf(a.y) << 16);
  o.y = f2bf(a.z) | ((unsigned)f2bf(a.w) << 16);
  o.z = f2bf(b.x) | ((unsigned)f2bf(b.y) << 16);
  o.w = f2bf(b.z) | ((unsigned)f2bf(b.w) << 16);
  *(uint4*)(dst + idx) = o;
}

// ---------------- bf16 MFMA GEMM: C = A(MxK) * W(NxK)^T + bias ----------------
#define BM 128
#define BN 128
#define BK 32

template<bool OUT_BF16>
__global__ __launch_bounds__(256) void gemm_nt(
    const unsigned short* __restrict__ A, const unsigned short* __restrict__ Bw,
    const float* __restrict__ bias, void* __restrict__ Cout, int M, int N, int K)
{
  __shared__ unsigned short As[BM * BK];
  __shared__ unsigned short Bs[BN * BK];
  int tid  = threadIdx.x;
  int lane = tid & 63;
  int wave = tid >> 6;
  int waveM = (wave >> 1) * 64;
  int waveN = (wave & 1) * 64;
  int lrow = lane & 15;
  int quad = lane >> 4;

  floatx4 acc[4][4];
  #pragma unroll
  for (int a_ = 0; a_ < 4; ++a_)
    #pragma unroll
    for (int b_ = 0; b_ < 4; ++b_) acc[a_][b_] = (floatx4){0.f, 0.f, 0.f, 0.f};

  const unsigned short* Ap = A  + (size_t)(blockIdx.y * BM) * K;
  const unsigned short* Bp = Bw + (size_t)(blockIdx.x * BN) * K;
  int r0 = tid >> 2;
  int c0 = (tid & 3) * 8;

  for (int k0 = 0; k0 < K; k0 += BK) {
    __syncthreads();
    *(uint4*)&As[r0 * BK + c0]        = *(const uint4*)&Ap[(size_t)r0 * K + k0 + c0];
    *(uint4*)&As[(r0 + 64) * BK + c0] = *(const uint4*)&Ap[(size_t)(r0 + 64) * K + k0 + c0];
    *(uint4*)&Bs[r0 * BK + c0]        = *(const uint4*)&Bp[(size_t)r0 * K + k0 + c0];
    *(uint4*)&Bs[(r0 + 64) * BK + c0] = *(const uint4*)&Bp[(size_t)(r0 + 64) * K + k0 + c0];
    __syncthreads();
    short8 af[4], bf[4];
    #pragma unroll
    for (int mt = 0; mt < 4; ++mt)
      af[mt] = *(const short8*)&As[(waveM + mt * 16 + lrow) * BK + quad * 8];
    #pragma unroll
    for (int nt = 0; nt < 4; ++nt)
      bf[nt] = *(const short8*)&Bs[(waveN + nt * 16 + lrow) * BK + quad * 8];
    #pragma unroll
    for (int mt = 0; mt < 4; ++mt)
      #pragma unroll
      for (int nt = 0; nt < 4; ++nt)
        acc[mt][nt] = __builtin_amdgcn_mfma_f32_16x16x32_bf16(af[mt], bf[nt], acc[mt][nt], 0, 0, 0);
  }

  int cm = blockIdx.y * BM + waveM;
  int cn = blockIdx.x * BN + waveN;
  #pragma unroll
  for (int nt = 0; nt < 4; ++nt) {
    int col = cn + nt * 16 + lrow;
    float bv = bias[col];
    #pragma unroll
    for (int mt = 0; mt < 4; ++mt) {
      #pragma unroll
      for (int r = 0; r < 4; ++r) {
        int row = cm + mt * 16 + quad * 4 + r;
        float v = acc[mt][nt][r] + bv;
        if (OUT_BF16) ((unsigned short*)Cout)[(size_t)row * N + col] = f2bf(v);
        else          ((float*)Cout)[(size_t)row * N + col] = v;
      }
    }
  }
}

// ---------------- K l2-normalize (in place, bf16) + Beta ----------------
__global__ __launch_bounds__(256) void norm_beta_kernel(
    unsigned short* __restrict__ Kb, const float* __restrict__ Wbeta,
    const float* __restrict__ bbeta, float* __restrict__ Beta)
{
  int w = blockIdx.x * 4 + (threadIdx.x >> 6);
  int lane = threadIdx.x & 63;
  unsigned short* kp = Kb + (size_t)w * D + lane * 8;
  uint4 raw = *(uint4*)kp;
  float kv[8]; unpack8(raw, kv);
  float ss = 0.f;
  #pragma unroll
  for (int m = 0; m < 8; ++m) ss += kv[m] * kv[m];
  ss = wave_allreduce(ss);
  float inv = 1.0f / fmaxf(sqrtf(ss), 1e-12f);
  const float* wb = Wbeta + lane * 8;
  float dotp = 0.f;
  #pragma unroll
  for (int m = 0; m < 8; ++m) { kv[m] *= inv; dotp += kv[m] * wb[m]; }
  uint4 o;
  o.x = f2bf(kv[0]) | ((unsigned)f2bf(kv[1]) << 16);
  o.y = f2bf(kv[2]) | ((unsigned)f2bf(kv[3]) << 16);
  o.z = f2bf(kv[4]) | ((unsigned)f2bf(kv[5]) << 16);
  o.w = f2bf(kv[6]) | ((unsigned)f2bf(kv[7]) << 16);
  *(uint4*)kp = o;
  dotp = wave_allreduce(dotp);
  if (lane == 0) Beta[w] = 1.0f / (1.0f + expf(-(dotp + bbeta[0])));
}

// ---------------- Gram kernel: G[w] = k_w . k_{w+1} (normalized K), 0 at batch ends ----------------
__global__ __launch_bounds__(256) void gram_kernel(
    const unsigned short* __restrict__ Kb, float* __restrict__ Gv)
{
  int w = blockIdx.x * 4 + (threadIdx.x >> 6);   // 0..16383
  int lane = threadIdx.x & 63;
  float g = 0.f;
  if ((w % T) != (T - 1)) {
    uint4 a = *(const uint4*)&Kb[(size_t)w * D + lane * 8];
    uint4 b = *(const uint4*)&Kb[(size_t)(w + 1) * D + lane * 8];
    float af[8], bf[8]; unpack8(a, af); unpack8(b, bf);
    #pragma unroll
    for (int m = 0; m < 8; ++m) g += af[m] * bf[m];
    g = wave_allreduce(g);
  }
  if (lane == 0) Gv[w] = g;
}

// ---------------- DeltaNet scan, pipelined ----------------
// One wave per (batch, state-row). Per step t (s = s_{t-1} at top):
//   p   = s . k_{t+1}             (partial; butterfly has a full iter of slack)
//   Sk  = R_t + c_{t-1}*G[t-1]    (Gram identity)
//   c   = beta_t*(v_t - Sk);  s += c*k_t;  P[t&7] += s . q_t
// Every 8 steps: batched recursive-halving o-reduce (10 shfl) + 1 store.
__global__ __launch_bounds__(256) void scan_kernel(
    const unsigned short* __restrict__ Qb, const unsigned short* __restrict__ Kb,
    const unsigned short* __restrict__ Vb, const float* __restrict__ Beta,
    const float* __restrict__ Gv, unsigned short* __restrict__ Ob)
{
  int w = blockIdx.x * 4 + (threadIdx.x >> 6);   // 0..4095
  int lane = threadIdx.x & 63;
  int b = w >> 9;          // batch
  int i = w & 511;         // state row
  int base = b * (T * D);
  int ro = lane * 8;
  const unsigned short* Kp = Kb + base + ro;
  const unsigned short* Qp = Qb + base + ro;
  const unsigned short* Vp = Vb + base + i;
  const float* Bp = Beta + b * T;
  const float* Gp = Gv + b * T;

  float s[8] = {0,0,0,0,0,0,0,0};
  float kfc[8], kfn[8];

  // preamble: invariants for t=0
  uint4 kr0 = *(const uint4*)&Kp[0];
  uint4 kr1 = *(const uint4*)&Kp[(size_t)1 * D];
  uint4 krn2 = *(const uint4*)&Kp[(size_t)2 * D];
  uint4 qr_cur = *(const uint4*)&Qp[0];
  uint4 qrn = *(const uint4*)&Qp[(size_t)1 * D];
  unpack8(kr0, kfc);
  unpack8(kr1, kfn);
  float R = 0.f, c_prev = 0.f, G_use = 0.f;
  float G_next = Gp[0];
  float beta_c = Bp[0], beta_n = Bp[1];
  float vi_c = bf2f(Vp[0]), vi_n = bf2f(Vp[(size_t)1 * D]);

  for (int t8 = 0; t8 < T; t8 += 8) {
    float P[8] = {0,0,0,0,0,0,0,0};
    #pragma unroll
    for (int j = 0; j < 8; ++j) {
      int t = t8 + j;
      // unpack q_t
      float qf[8]; unpack8(qr_cur, qf);
      // p-dot on pre-update s (for R_{t+1}); butterfly gets ~1 iter slack
      float p = 0.f;
      #pragma unroll
      for (int m = 0; m < 8; ++m) p += s[m] * kfn[m];
      float Rn = wave_allreduce(p);
      // Sk via Gram identity, then c
      float Sk = fmaf(c_prev, G_use, R);
      float c  = beta_c * (vi_c - Sk);
      // state update + o partial
      #pragma unroll
      for (int m = 0; m < 8; ++m) { s[m] = fmaf(c, kfc[m], s[m]); P[j] = fmaf(s[m], qf[m], P[j]); }
      // prefetch for t+2 / t+3
      int tk = t + 3; tk = tk < T ? tk : T - 1;
      int tq = t + 2; tq = tq < T ? tq : T - 1;
      uint4 kr_new = *(const uint4*)&Kp[(size_t)tk * D];
      uint4 qr_new = *(const uint4*)&Qp[(size_t)tq * D];
      float beta_new = Bp[tq];
      float vi_new = bf2f(Vp[(size_t)tq * D]);
      int tg = t + 1; tg = tg < T ? tg : T - 1;
      float G_new = Gp[tg];
      // rotate
      R = Rn; c_prev = c; G_use = G_next; G_next = G_new;
      #pragma unroll
      for (int m = 0; m < 8; ++m) kfc[m] = kfn[m];
      unpack8(krn2, kfn);
      krn2 = kr_new;
      qr_cur = qrn; qrn = qr_new;
      beta_c = beta_n; beta_n = beta_new;
      vi_c = vi_n; vi_n = vi_new;
    }
    // batched o-reduce: recursive halving over 8 values, then 3-stage butterfly
    bool l1 = (lane & 1), l2 = (lane & 2), l4 = (lane & 4);
    float A0, A1, A2, A3, B0, B1, C;
    {
      float s0 = l1 ? P[0] : P[1], s1 = l1 ? P[2] : P[3];
      float s2 = l1 ? P[4] : P[5], s3 = l1 ? P[6] : P[7];
      A0 = (l1 ? P[1] : P[0]) + __shfl_xor(s0, 1);
      A1 = (l1 ? P[3] : P[2]) + __shfl_xor(s1, 1);
      A2 = (l1 ? P[5] : P[4]) + __shfl_xor(s2, 1);
      A3 = (l1 ? P[7] : P[6]) + __shfl_xor(s3, 1);
    }
    {
      float s0 = l2 ? A0 : A1, s1 = l2 ? A2 : A3;
      B0 = (l2 ? A1 : A0) + __shfl_xor(s0, 2);
      B1 = (l2 ? A3 : A2) + __shfl_xor(s1, 2);
    }
    {
      float s0 = l4 ? B0 : B1;
      C = (l4 ? B1 : B0) + __shfl_xor(s0, 4);
    }
    C += __shfl_xor(C, 8);
    C += __shfl_xor(C, 16);
    C += __shfl_xor(C, 32);
    if (lane < 8) Ob[base + (size_t)(t8 + lane) * D + i] = f2bf(C);
  }
}

extern "C" void kernel_launch(void* const* d_in, const int* in_sizes, int n_in,
                              void* d_out, int out_size, void* d_ws, size_t ws_size,
                              hipStream_t stream) {
  const float* x     = (const float*)d_in[0];
  const float* Wq    = (const float*)d_in[1];
  const float* bq    = (const float*)d_in[2];
  const float* Wk    = (const float*)d_in[3];
  const float* bk    = (const float*)d_in[4];
  const float* Wv    = (const float*)d_in[5];
  const float* bv    = (const float*)d_in[6];
  const float* Wbeta = (const float*)d_in[7];
  const float* bbeta = (const float*)d_in[8];
  const float* Wo    = (const float*)d_in[9];
  const float* bo    = (const float*)d_in[10];

  const size_t NE = (size_t)M_ROWS * D;
  unsigned short* Qb  = (unsigned short*)d_ws;
  unsigned short* Kb  = Qb + NE;
  unsigned short* Vb  = Kb + NE;
  unsigned short* Xb  = Vb + NE;                   // x bf16; reused as pre-Wo output
  unsigned short* Wqb = Xb + NE;
  unsigned short* Wkb = Wqb + D * D;
  unsigned short* Wvb = Wkb + D * D;
  unsigned short* Wob = Wvb + D * D;
  float* Beta = (float*)(Wob + D * D);             // 16384 f32
  float* Gv   = Beta + M_ROWS;                     // 16384 f32

  cast_kernel<<<(int)(NE / 2048), 256, 0, stream>>>(x, Xb, (int)NE);
  cast_kernel<<<(D * D) / 2048, 256, 0, stream>>>(Wq, Wqb, D * D);
  cast_kernel<<<(D * D) / 2048, 256, 0, stream>>>(Wk, Wkb, D * D);
  cast_kernel<<<(D * D) / 2048, 256, 0, stream>>>(Wv, Wvb, D * D);
  cast_kernel<<<(D * D) / 2048, 256, 0, stream>>>(Wo, Wob, D * D);

  dim3 gg(D / BN, M_ROWS / BM);  // (4, 128)
  gemm_nt<true><<<gg, 256, 0, stream>>>(Xb, Wqb, bq, Qb, M_ROWS, D, D);
  gemm_nt<true><<<gg, 256, 0, stream>>>(Xb, Wkb, bk, Kb, M_ROWS, D, D);
  gemm_nt<true><<<gg, 256, 0, stream>>>(Xb, Wvb, bv, Vb, M_ROWS, D, D);

  norm_beta_kernel<<<M_ROWS / 4, 256, 0, stream>>>(Kb, Wbeta, bbeta, Beta);
  gram_kernel<<<M_ROWS / 4, 256, 0, stream>>>(Kb, Gv);

  scan_kernel<<<(BATCH * D) / 4, 256, 0, stream>>>(Qb, Kb, Vb, Beta, Gv, Xb);

  gemm_nt<false><<<gg, 256, 0, stream>>>(Xb, Wob, bo, (float*)d_out, M_ROWS, D, D);
}

// Round 4
// 484.276 us; speedup vs baseline: 3.4020x; 2.7374x over previous
//
#include <hip/hip_runtime.h>

#define D 512
#define T 2048
#define BATCH 8
#define M_ROWS (BATCH*T)   // 16384
#define CHK 64             // chunk length
#define NCHB 32            // chunks per batch
#define NCHUNK 256         // total chunks

typedef __attribute__((ext_vector_type(8))) short short8;
typedef __attribute__((ext_vector_type(4))) float floatx4;

__device__ __forceinline__ unsigned short f2bf(float f) {
  unsigned int u = __float_as_uint(f);
  u += 0x7FFFu + ((u >> 16) & 1u);          // RNE
  return (unsigned short)(u >> 16);
}
__device__ __forceinline__ float bf2f(unsigned int h) {
  return __uint_as_float(h << 16);
}
__device__ __forceinline__ float wave_allreduce(float v) {
  #pragma unroll
  for (int m = 32; m; m >>= 1) v += __shfl_xor(v, m, 64);
  return v;
}
__device__ __forceinline__ void unpack8(uint4 r, float f[8]) {
  f[0] = bf2f(r.x & 0xffffu); f[1] = bf2f(r.x >> 16);
  f[2] = bf2f(r.y & 0xffffu); f[3] = bf2f(r.y >> 16);
  f[4] = bf2f(r.z & 0xffffu); f[5] = bf2f(r.z >> 16);
  f[6] = bf2f(r.w & 0xffffu); f[7] = bf2f(r.w >> 16);
}

// ---------------- f32 -> bf16 cast ----------------
__global__ __launch_bounds__(256) void cast_kernel(const float* __restrict__ src,
                                                   unsigned short* __restrict__ dst, int n) {
  int idx = (blockIdx.x * 256 + threadIdx.x) * 8;
  if (idx >= n) return;
  const float4* sp = (const float4*)(src + idx);
  float4 a = sp[0], b = sp[1];
  uint4 o;
  o.x = f2bf(a.x) | ((unsigned)f2bf(a.y) << 16);
  o.y = f2bf(a.z) | ((unsigned)f2bf(a.w) << 16);
  o.z = f2bf(b.x) | ((unsigned)f2bf(b.y) << 16);
  o.w = f2bf(b.z) | ((unsigned)f2bf(b.w) << 16);
  *(uint4*)(dst + idx) = o;
}

// ---------------- bf16 MFMA GEMM: C = A(MxK) * W(NxK)^T + bias ----------------
#define BM 128
#define BN 128
#define BK 32

template<bool OUT_BF16>
__global__ __launch_bounds__(256) void gemm_nt(
    const unsigned short* __restrict__ A, const unsigned short* __restrict__ Bw,
    const float* __restrict__ bias, void* __restrict__ Cout, int M, int N, int K)
{
  __shared__ __align__(16) unsigned short As[BM * BK];
  __shared__ __align__(16) unsigned short Bs[BN * BK];
  int tid  = threadIdx.x;
  int lane = tid & 63;
  int wave = tid >> 6;
  int waveM = (wave >> 1) * 64;
  int waveN = (wave & 1) * 64;
  int lrow = lane & 15;
  int quad = lane >> 4;

  floatx4 acc[4][4];
  #pragma unroll
  for (int a_ = 0; a_ < 4; ++a_)
    #pragma unroll
    for (int b_ = 0; b_ < 4; ++b_) acc[a_][b_] = (floatx4){0.f, 0.f, 0.f, 0.f};

  const unsigned short* Ap = A  + (size_t)(blockIdx.y * BM) * K;
  const unsigned short* Bp = Bw + (size_t)(blockIdx.x * BN) * K;
  int r0 = tid >> 2;
  int c0 = (tid & 3) * 8;

  for (int k0 = 0; k0 < K; k0 += BK) {
    __syncthreads();
    *(uint4*)&As[r0 * BK + c0]        = *(const uint4*)&Ap[(size_t)r0 * K + k0 + c0];
    *(uint4*)&As[(r0 + 64) * BK + c0] = *(const uint4*)&Ap[(size_t)(r0 + 64) * K + k0 + c0];
    *(uint4*)&Bs[r0 * BK + c0]        = *(const uint4*)&Bp[(size_t)r0 * K + k0 + c0];
    *(uint4*)&Bs[(r0 + 64) * BK + c0] = *(const uint4*)&Bp[(size_t)(r0 + 64) * K + k0 + c0];
    __syncthreads();
    short8 af[4], bf[4];
    #pragma unroll
    for (int mt = 0; mt < 4; ++mt)
      af[mt] = *(const short8*)&As[(waveM + mt * 16 + lrow) * BK + quad * 8];
    #pragma unroll
    for (int nt = 0; nt < 4; ++nt)
      bf[nt] = *(const short8*)&Bs[(waveN + nt * 16 + lrow) * BK + quad * 8];
    #pragma unroll
    for (int mt = 0; mt < 4; ++mt)
      #pragma unroll
      for (int nt = 0; nt < 4; ++nt)
        acc[mt][nt] = __builtin_amdgcn_mfma_f32_16x16x32_bf16(af[mt], bf[nt], acc[mt][nt], 0, 0, 0);
  }

  int cm = blockIdx.y * BM + waveM;
  int cn = blockIdx.x * BN + waveN;
  #pragma unroll
  for (int nt = 0; nt < 4; ++nt) {
    int col = cn + nt * 16 + lrow;
    float bv = bias[col];
    #pragma unroll
    for (int mt = 0; mt < 4; ++mt) {
      #pragma unroll
      for (int r = 0; r < 4; ++r) {
        int row = cm + mt * 16 + quad * 4 + r;
        float v = acc[mt][nt][r] + bv;
        if (OUT_BF16) ((unsigned short*)Cout)[(size_t)row * N + col] = f2bf(v);
        else          ((float*)Cout)[(size_t)row * N + col] = v;
      }
    }
  }
}

// ---------------- K l2-normalize (in place) + Beta ----------------
__global__ __launch_bounds__(256) void norm_beta_kernel(
    unsigned short* __restrict__ Kb, const float* __restrict__ Wbeta,
    const float* __restrict__ bbeta, float* __restrict__ Beta)
{
  int w = blockIdx.x * 4 + (threadIdx.x >> 6);
  int lane = threadIdx.x & 63;
  unsigned short* kp = Kb + (size_t)w * D + lane * 8;
  uint4 raw = *(uint4*)kp;
  float kv[8]; unpack8(raw, kv);
  float ss = 0.f;
  #pragma unroll
  for (int m = 0; m < 8; ++m) ss += kv[m] * kv[m];
  ss = wave_allreduce(ss);
  float inv = 1.0f / fmaxf(sqrtf(ss), 1e-12f);
  const float* wb = Wbeta + lane * 8;
  float dotp = 0.f;
  #pragma unroll
  for (int m = 0; m < 8; ++m) { kv[m] *= inv; dotp += kv[m] * wb[m]; }
  uint4 o;
  o.x = f2bf(kv[0]) | ((unsigned)f2bf(kv[1]) << 16);
  o.y = f2bf(kv[2]) | ((unsigned)f2bf(kv[3]) << 16);
  o.z = f2bf(kv[4]) | ((unsigned)f2bf(kv[5]) << 16);
  o.w = f2bf(kv[6]) | ((unsigned)f2bf(kv[7]) << 16);
  *(uint4*)kp = o;
  dotp = wave_allreduce(dotp);
  if (lane == 0) Beta[w] = 1.0f / (1.0f + expf(-(dotp + bbeta[0])));
}

// ---------------- per-chunk transpose: KT[cb][dk][t] = K[cb*64+t][dk] ----------------
__global__ __launch_bounds__(256) void transpose_k(
    const unsigned short* __restrict__ Kb, unsigned short* __restrict__ KT)
{
  __shared__ __align__(16) unsigned short Kc[64 * 520];
  int cb = blockIdx.x, tid = threadIdx.x;
  const unsigned short* src = Kb + (size_t)cb * 64 * 512;
  #pragma unroll
  for (int it = 0; it < 16; ++it) {
    int e = it * 2048 + tid * 8;
    int row = e >> 9, col = e & 511;
    *(uint4*)&Kc[row * 520 + col] = *(const uint4*)&src[row * 512 + col];
  }
  __syncthreads();
  unsigned short* dst = KT + (size_t)cb * 32768;
  #pragma unroll
  for (int it = 0; it < 16; ++it) {
    int e = it * 2048 + tid * 8;
    int dk = e >> 6, t0 = e & 63;
    uint4 o;
    unsigned short tv[8];
    #pragma unroll
    for (int u = 0; u < 8; ++u) tv[u] = Kc[(t0 + u) * 520 + dk];
    o.x = tv[0] | ((unsigned)tv[1] << 16);
    o.y = tv[2] | ((unsigned)tv[3] << 16);
    o.z = tv[4] | ((unsigned)tv[5] << 16);
    o.w = tv[6] | ((unsigned)tv[7] << 16);
    *(uint4*)&dst[e] = o;
  }
}

// ---------------- per-chunk Gram: A = strict_tril(beta_t * K K^T) f32, Ms = tril(Q K^T) bf16 ----------------
__global__ __launch_bounds__(256) void gram_kernel(
    const unsigned short* __restrict__ Qb, const unsigned short* __restrict__ Kb,
    const float* __restrict__ Beta, float* __restrict__ Abuf,
    unsigned short* __restrict__ Msb)
{
  int cb = blockIdx.x, tid = threadIdx.x, lane = tid & 63, w = tid >> 6;
  int lr = lane & 15, quad = lane >> 4;
  const unsigned short* kc = Kb + (size_t)cb * 64 * 512;
  const unsigned short* qc = Qb + (size_t)cb * 64 * 512;
  floatx4 accK[4], accQ[4];
  #pragma unroll
  for (int nt = 0; nt < 4; ++nt) { accK[nt] = (floatx4){0,0,0,0}; accQ[nt] = (floatx4){0,0,0,0}; }
  #pragma unroll
  for (int ks = 0; ks < 16; ++ks) {
    short8 ak = *(const short8*)&kc[(w * 16 + lr) * 512 + ks * 32 + quad * 8];
    short8 aq = *(const short8*)&qc[(w * 16 + lr) * 512 + ks * 32 + quad * 8];
    short8 bk[4];
    #pragma unroll
    for (int nt = 0; nt < 4; ++nt)
      bk[nt] = *(const short8*)&kc[(nt * 16 + lr) * 512 + ks * 32 + quad * 8];
    #pragma unroll
    for (int nt = 0; nt < 4; ++nt) {
      accK[nt] = __builtin_amdgcn_mfma_f32_16x16x32_bf16(ak, bk[nt], accK[nt], 0, 0, 0);
      accQ[nt] = __builtin_amdgcn_mfma_f32_16x16x32_bf16(aq, bk[nt], accQ[nt], 0, 0, 0);
    }
  }
  #pragma unroll
  for (int nt = 0; nt < 4; ++nt)
    #pragma unroll
    for (int r = 0; r < 4; ++r) {
      int t = w * 16 + quad * 4 + r;
      int j = nt * 16 + lr;
      float bt = Beta[cb * 64 + t];
      Abuf[(size_t)cb * 4096 + t * 64 + j] = (j < t) ? bt * accK[nt][r] : 0.f;
      Msb[(size_t)cb * 4096 + t * 64 + j]  = f2bf((j <= t) ? accQ[nt][r] : 0.f);
    }
}

// ---------------- Tinv = (I+A)^{-1}, wave per chunk; stores Tinvbeta[t][u] = Tinv[t][u]*beta_u (bf16) ----------------
__global__ __launch_bounds__(256) void tinv_kernel(
    const float* __restrict__ Abuf, const float* __restrict__ Beta,
    unsigned short* __restrict__ Tib)
{
  __shared__ float XL[4 * 4096];
  int tid = threadIdx.x, w = tid >> 6, lane = tid & 63;
  int cb = blockIdx.x * 4 + w;
  float* X = XL + w * 4096;
  #pragma unroll
  for (int j = 0; j < 64; ++j) X[j * 64 + lane] = 0.f;   // so A=0 rows contribute 0, never NaN
  float bl = Beta[cb * 64 + lane];
  const float* Ab = Abuf + (size_t)cb * 4096;
  unsigned short* To = Tib + (size_t)cb * 4096;
  for (int t = 0; t < 64; ++t) {
    float y = (lane == t) ? 1.f : 0.f;
    const float* Ar = Ab + t * 64;
    for (int jb = 0; jb < 64; jb += 8) {
      float av[8], xv[8];
      #pragma unroll
      for (int u = 0; u < 8; ++u) { av[u] = Ar[jb + u]; xv[u] = X[(jb + u) * 64 + lane]; }
      #pragma unroll
      for (int u = 0; u < 8; ++u) y = fmaf(-av[u], xv[u], y);
    }
    X[t * 64 + lane] = y;
    To[t * 64 + lane] = f2bf(y * bl);
  }
}

// ---------------- Wneg = -Tinvbeta*K, Ubar = Tinvbeta*V (per chunk, bf16 out) ----------------
__global__ __launch_bounds__(256) void wu_kernel(
    const unsigned short* __restrict__ Tib, const unsigned short* __restrict__ KT,
    const unsigned short* __restrict__ Vb, unsigned short* __restrict__ Wneg,
    unsigned short* __restrict__ Ubar)
{
  __shared__ __align__(16) unsigned short Vc[64 * 520];
  int cb = blockIdx.x, tid = threadIdx.x, lane = tid & 63, w = tid >> 6;
  int lr = lane & 15, quad = lane >> 4;
  const unsigned short* vsrc = Vb + (size_t)cb * 64 * 512;
  #pragma unroll
  for (int it = 0; it < 16; ++it) {
    int e = it * 2048 + tid * 8, row = e >> 9, col = e & 511;
    *(uint4*)&Vc[row * 520 + col] = *(const uint4*)&vsrc[row * 512 + col];
  }
  __syncthreads();
  short8 af[2];
  #pragma unroll
  for (int ks = 0; ks < 2; ++ks)
    af[ks] = *(const short8*)&Tib[(size_t)cb * 4096 + (w * 16 + lr) * 64 + ks * 32 + quad * 8];
  const unsigned short* ktc = KT + (size_t)cb * 32768;
  for (int nt = 0; nt < 32; ++nt) {
    floatx4 aw = (floatx4){0,0,0,0}, au = (floatx4){0,0,0,0};
    #pragma unroll
    for (int ks = 0; ks < 2; ++ks) {
      short8 bk = *(const short8*)&ktc[(nt * 16 + lr) * 64 + ks * 32 + quad * 8];
      short8 bv;
      #pragma unroll
      for (int u = 0; u < 8; ++u)
        bv[u] = (short)Vc[(ks * 32 + quad * 8 + u) * 520 + nt * 16 + lr];
      aw = __builtin_amdgcn_mfma_f32_16x16x32_bf16(af[ks], bk, aw, 0, 0, 0);
      au = __builtin_amdgcn_mfma_f32_16x16x32_bf16(af[ks], bv, au, 0, 0, 0);
    }
    #pragma unroll
    for (int r = 0; r < 4; ++r) {
      int t = w * 16 + quad * 4 + r, dd = nt * 16 + lr;
      Wneg[((size_t)cb * 64 + t) * 512 + dd] = f2bf(-aw[r]);
      Ubar[((size_t)cb * 64 + t) * 512 + dd] = f2bf(au[r]);
    }
  }
}

// ---------------- sequential chunk scan: block = (batch, 16-row v-slice), S in regs ----------------
// per chunk: U = Ubar + Wneg*S^T ; O = Q*S^T + Ms*U ; S += U^T*K
__global__ __launch_bounds__(256) void seq_kernel(
    const unsigned short* __restrict__ Wneg, const unsigned short* __restrict__ Qb,
    const unsigned short* __restrict__ Ubar, const unsigned short* __restrict__ Msb,
    const unsigned short* __restrict__ KT, unsigned short* __restrict__ Ob)
{
  __shared__ __align__(16) unsigned short Sb[16 * 520];
  __shared__ __align__(16) unsigned short Ut[16 * 72];
  int blk = blockIdx.x;
  int b = blk >> 5, vs = blk & 31;
  int vg0 = vs * 16;
  int tid = threadIdx.x, lane = tid & 63, w = tid >> 6;
  int lr = lane & 15, quad = lane >> 4;
  floatx4 sacc[8];
  #pragma unroll
  for (int nt = 0; nt < 8; ++nt) sacc[nt] = (floatx4){0,0,0,0};

  for (int ch = 0; ch < NCHB; ++ch) {
    int cb = b * NCHB + ch;
    size_t tokb = (size_t)cb * 64;
    // stage S^T (bf16) into LDS: Sb[v][dk], v=quad*4+r, dk=w*128+nt*16+lr
    #pragma unroll
    for (int nt = 0; nt < 8; ++nt)
      #pragma unroll
      for (int r = 0; r < 4; ++r)
        Sb[(quad * 4 + r) * 520 + w * 128 + nt * 16 + lr] = f2bf(sacc[nt][r]);
    __syncthreads();
    // U-GEMM: rows t=w*16.., cols v-slice; acc init = Ubar
    floatx4 du;
    #pragma unroll
    for (int r = 0; r < 4; ++r)
      du[r] = bf2f(Ubar[(tokb + w * 16 + quad * 4 + r) * 512 + vg0 + lr]);
    #pragma unroll
    for (int ks = 0; ks < 16; ++ks) {
      short8 a = *(const short8*)&Wneg[(tokb + w * 16 + lr) * 512 + ks * 32 + quad * 8];
      short8 bfr = *(const short8*)&Sb[lr * 520 + ks * 32 + quad * 8];
      du = __builtin_amdgcn_mfma_f32_16x16x32_bf16(a, bfr, du, 0, 0, 0);
    }
    #pragma unroll
    for (int r = 0; r < 4; ++r)
      Ut[lr * 72 + w * 16 + quad * 4 + r] = f2bf(du[r]);
    __syncthreads();
    // O-GEMM: Q*S^T (16 ksteps) + Ms*U (2 ksteps)
    floatx4 doo = (floatx4){0,0,0,0};
    #pragma unroll
    for (int ks = 0; ks < 16; ++ks) {
      short8 a = *(const short8*)&Qb[(tokb + w * 16 + lr) * 512 + ks * 32 + quad * 8];
      short8 bfr = *(const short8*)&Sb[lr * 520 + ks * 32 + quad * 8];
      doo = __builtin_amdgcn_mfma_f32_16x16x32_bf16(a, bfr, doo, 0, 0, 0);
    }
    short8 a2[2];
    #pragma unroll
    for (int ks = 0; ks < 2; ++ks)
      a2[ks] = *(const short8*)&Ut[lr * 72 + ks * 32 + quad * 8];
    #pragma unroll
    for (int ks = 0; ks < 2; ++ks) {
      short8 a = *(const short8*)&Msb[(size_t)cb * 4096 + (w * 16 + lr) * 64 + ks * 32 + quad * 8];
      doo = __builtin_amdgcn_mfma_f32_16x16x32_bf16(a, a2[ks], doo, 0, 0, 0);
    }
    #pragma unroll
    for (int r = 0; r < 4; ++r)
      Ob[(tokb + w * 16 + quad * 4 + r) * 512 + vg0 + lr] = f2bf(doo[r]);
    // S-GEMM: sacc += U^T * K  (A = Ut[v][t], B = KT[dk][t])
    #pragma unroll
    for (int nt = 0; nt < 8; ++nt) {
      #pragma unroll
      for (int ks = 0; ks < 2; ++ks) {
        int dk = w * 128 + nt * 16 + lr;
        short8 bfr = *(const short8*)&KT[(size_t)cb * 32768 + dk * 64 + ks * 32 + quad * 8];
        sacc[nt] = __builtin_amdgcn_mfma_f32_16x16x32_bf16(a2[ks], bfr, sacc[nt], 0, 0, 0);
      }
    }
    __syncthreads();
  }
}

extern "C" void kernel_launch(void* const* d_in, const int* in_sizes, int n_in,
                              void* d_out, int out_size, void* d_ws, size_t ws_size,
                              hipStream_t stream) {
  const float* x     = (const float*)d_in[0];
  const float* Wq    = (const float*)d_in[1];
  const float* bq    = (const float*)d_in[2];
  const float* Wk    = (const float*)d_in[3];
  const float* bk    = (const float*)d_in[4];
  const float* Wv    = (const float*)d_in[5];
  const float* bv    = (const float*)d_in[6];
  const float* Wbeta = (const float*)d_in[7];
  const float* bbeta = (const float*)d_in[8];
  const float* Wo    = (const float*)d_in[9];
  const float* bo    = (const float*)d_in[10];

  const size_t NE = (size_t)M_ROWS * D;   // 8,388,608
  const size_t DD = (size_t)D * D;
  unsigned short* Qb  = (unsigned short*)d_ws;
  unsigned short* Kb  = Qb + NE;          // later: Ubar
  unsigned short* Vb  = Kb + NE;          // later: O
  unsigned short* Xb  = Vb + NE;          // x bf16; later: Wneg
  unsigned short* Wqb = Xb + NE;
  unsigned short* Wkb = Wqb + DD;
  unsigned short* Wvb = Wkb + DD;
  unsigned short* Wob = Wvb + DD;
  float* Beta = (float*)(Wob + DD);               // 16384 f32
  unsigned short* KT  = (unsigned short*)(Beta + M_ROWS);  // NE shorts
  float* Abuf = (float*)(KT + NE);                // 256*4096 f32
  unsigned short* Msb = (unsigned short*)(Abuf + (size_t)NCHUNK * 4096);
  unsigned short* Tib = Msb + (size_t)NCHUNK * 4096;       // total ~92 MB

  cast_kernel<<<(int)(NE / 2048), 256, 0, stream>>>(x, Xb, (int)NE);
  cast_kernel<<<(int)(DD / 2048), 256, 0, stream>>>(Wq, Wqb, (int)DD);
  cast_kernel<<<(int)(DD / 2048), 256, 0, stream>>>(Wk, Wkb, (int)DD);
  cast_kernel<<<(int)(DD / 2048), 256, 0, stream>>>(Wv, Wvb, (int)DD);
  cast_kernel<<<(int)(DD / 2048), 256, 0, stream>>>(Wo, Wob, (int)DD);

  dim3 gg(D / BN, M_ROWS / BM);  // (4, 128)
  gemm_nt<true><<<gg, 256, 0, stream>>>(Xb, Wqb, bq, Qb, M_ROWS, D, D);
  gemm_nt<true><<<gg, 256, 0, stream>>>(Xb, Wkb, bk, Kb, M_ROWS, D, D);
  gemm_nt<true><<<gg, 256, 0, stream>>>(Xb, Wvb, bv, Vb, M_ROWS, D, D);

  norm_beta_kernel<<<M_ROWS / 4, 256, 0, stream>>>(Kb, Wbeta, bbeta, Beta);

  transpose_k<<<NCHUNK, 256, 0, stream>>>(Kb, KT);
  gram_kernel<<<NCHUNK, 256, 0, stream>>>(Qb, Kb, Beta, Abuf, Msb);
  tinv_kernel<<<NCHUNK / 4, 256, 0, stream>>>(Abuf, Beta, Tib);
  wu_kernel<<<NCHUNK, 256, 0, stream>>>(Tib, KT, Vb, /*Wneg=*/Xb, /*Ubar=*/Kb);

  seq_kernel<<<NCHUNK, 256, 0, stream>>>(/*Wneg=*/Xb, Qb, /*Ubar=*/Kb, Msb, KT, /*O=*/Vb);

  gemm_nt<false><<<gg, 256, 0, stream>>>(Vb, Wob, bo, (float*)d_out, M_ROWS, D, D);
}

// Round 5
// 478.662 us; speedup vs baseline: 3.4419x; 1.0117x over previous
//
#include <hip/hip_runtime.h>

#define D 512
#define T 2048
#define BATCH 8
#define M_ROWS (BATCH*T)   // 16384
#define CHK 64             // chunk length
#define NCHB 32            // chunks per batch
#define NCHUNK 256         // total chunks

typedef __attribute__((ext_vector_type(8))) short short8;
typedef __attribute__((ext_vector_type(4))) float floatx4;

__device__ __forceinline__ unsigned short f2bf(float f) {
  unsigned int u = __float_as_uint(f);
  u += 0x7FFFu + ((u >> 16) & 1u);          // RNE
  return (unsigned short)(u >> 16);
}
__device__ __forceinline__ float bf2f(unsigned int h) {
  return __uint_as_float(h << 16);
}
__device__ __forceinline__ float wave_allreduce(float v) {
  #pragma unroll
  for (int m = 32; m; m >>= 1) v += __shfl_xor(v, m, 64);
  return v;
}
__device__ __forceinline__ void unpack8(uint4 r, float f[8]) {
  f[0] = bf2f(r.x & 0xffffu); f[1] = bf2f(r.x >> 16);
  f[2] = bf2f(r.y & 0xffffu); f[3] = bf2f(r.y >> 16);
  f[4] = bf2f(r.z & 0xffffu); f[5] = bf2f(r.z >> 16);
  f[6] = bf2f(r.w & 0xffffu); f[7] = bf2f(r.w >> 16);
}

// ---------------- f32 -> bf16 cast ----------------
__global__ __launch_bounds__(256) void cast_kernel(const float* __restrict__ src,
                                                   unsigned short* __restrict__ dst, int n) {
  int idx = (blockIdx.x * 256 + threadIdx.x) * 8;
  if (idx >= n) return;
  const float4* sp = (const float4*)(src + idx);
  float4 a = sp[0], b = sp[1];
  uint4 o;
  o.x = f2bf(a.x) | ((unsigned)f2bf(a.y) << 16);
  o.y = f2bf(a.z) | ((unsigned)f2bf(a.w) << 16);
  o.z = f2bf(b.x) | ((unsigned)f2bf(b.y) << 16);
  o.w = f2bf(b.z) | ((unsigned)f2bf(b.w) << 16);
  *(uint4*)(dst + idx) = o;
}

// ---------------- bf16 MFMA GEMM: C = A(MxK) * W(NxK)^T + bias ----------------
#define BM 128
#define BN 128
#define BK 32

template<bool OUT_BF16>
__global__ __launch_bounds__(256) void gemm_nt(
    const unsigned short* __restrict__ A, const unsigned short* __restrict__ Bw,
    const float* __restrict__ bias, void* __restrict__ Cout, int M, int N, int K)
{
  __shared__ __align__(16) unsigned short As[BM * BK];
  __shared__ __align__(16) unsigned short Bs[BN * BK];
  int tid  = threadIdx.x;
  int lane = tid & 63;
  int wave = tid >> 6;
  int waveM = (wave >> 1) * 64;
  int waveN = (wave & 1) * 64;
  int lrow = lane & 15;
  int quad = lane >> 4;

  floatx4 acc[4][4];
  #pragma unroll
  for (int a_ = 0; a_ < 4; ++a_)
    #pragma unroll
    for (int b_ = 0; b_ < 4; ++b_) acc[a_][b_] = (floatx4){0.f, 0.f, 0.f, 0.f};

  const unsigned short* Ap = A  + (size_t)(blockIdx.y * BM) * K;
  const unsigned short* Bp = Bw + (size_t)(blockIdx.x * BN) * K;
  int r0 = tid >> 2;
  int c0 = (tid & 3) * 8;

  for (int k0 = 0; k0 < K; k0 += BK) {
    __syncthreads();
    *(uint4*)&As[r0 * BK + c0]        = *(const uint4*)&Ap[(size_t)r0 * K + k0 + c0];
    *(uint4*)&As[(r0 + 64) * BK + c0] = *(const uint4*)&Ap[(size_t)(r0 + 64) * K + k0 + c0];
    *(uint4*)&Bs[r0 * BK + c0]        = *(const uint4*)&Bp[(size_t)r0 * K + k0 + c0];
    *(uint4*)&Bs[(r0 + 64) * BK + c0] = *(const uint4*)&Bp[(size_t)(r0 + 64) * K + k0 + c0];
    __syncthreads();
    short8 af[4], bf[4];
    #pragma unroll
    for (int mt = 0; mt < 4; ++mt)
      af[mt] = *(const short8*)&As[(waveM + mt * 16 + lrow) * BK + quad * 8];
    #pragma unroll
    for (int nt = 0; nt < 4; ++nt)
      bf[nt] = *(const short8*)&Bs[(waveN + nt * 16 + lrow) * BK + quad * 8];
    #pragma unroll
    for (int mt = 0; mt < 4; ++mt)
      #pragma unroll
      for (int nt = 0; nt < 4; ++nt)
        acc[mt][nt] = __builtin_amdgcn_mfma_f32_16x16x32_bf16(af[mt], bf[nt], acc[mt][nt], 0, 0, 0);
  }

  int cm = blockIdx.y * BM + waveM;
  int cn = blockIdx.x * BN + waveN;
  #pragma unroll
  for (int nt = 0; nt < 4; ++nt) {
    int col = cn + nt * 16 + lrow;
    float bv = bias[col];
    #pragma unroll
    for (int mt = 0; mt < 4; ++mt) {
      #pragma unroll
      for (int r = 0; r < 4; ++r) {
        int row = cm + mt * 16 + quad * 4 + r;
        float v = acc[mt][nt][r] + bv;
        if (OUT_BF16) ((unsigned short*)Cout)[(size_t)row * N + col] = f2bf(v);
        else          ((float*)Cout)[(size_t)row * N + col] = v;
      }
    }
  }
}

// ---------------- K l2-normalize (in place) + Beta ----------------
__global__ __launch_bounds__(256) void norm_beta_kernel(
    unsigned short* __restrict__ Kb, const float* __restrict__ Wbeta,
    const float* __restrict__ bbeta, float* __restrict__ Beta)
{
  int w = blockIdx.x * 4 + (threadIdx.x >> 6);
  int lane = threadIdx.x & 63;
  unsigned short* kp = Kb + (size_t)w * D + lane * 8;
  uint4 raw = *(uint4*)kp;
  float kv[8]; unpack8(raw, kv);
  float ss = 0.f;
  #pragma unroll
  for (int m = 0; m < 8; ++m) ss += kv[m] * kv[m];
  ss = wave_allreduce(ss);
  float inv = 1.0f / fmaxf(sqrtf(ss), 1e-12f);
  const float* wb = Wbeta + lane * 8;
  float dotp = 0.f;
  #pragma unroll
  for (int m = 0; m < 8; ++m) { kv[m] *= inv; dotp += kv[m] * wb[m]; }
  uint4 o;
  o.x = f2bf(kv[0]) | ((unsigned)f2bf(kv[1]) << 16);
  o.y = f2bf(kv[2]) | ((unsigned)f2bf(kv[3]) << 16);
  o.z = f2bf(kv[4]) | ((unsigned)f2bf(kv[5]) << 16);
  o.w = f2bf(kv[6]) | ((unsigned)f2bf(kv[7]) << 16);
  *(uint4*)kp = o;
  dotp = wave_allreduce(dotp);
  if (lane == 0) Beta[w] = 1.0f / (1.0f + expf(-(dotp + bbeta[0])));
}

// ---------------- per-chunk transpose of K and V: XT[cb][dd][t] = X[cb*64+t][dd] ----------------
__global__ __launch_bounds__(256) void transpose_kv(
    const unsigned short* __restrict__ Kb, const unsigned short* __restrict__ Vb,
    unsigned short* __restrict__ KT, unsigned short* __restrict__ VT)
{
  __shared__ __align__(16) unsigned short Kc[64 * 520];
  int cb = blockIdx.x & 255, tid = threadIdx.x;
  const unsigned short* src = (blockIdx.x < 256 ? Kb : Vb) + (size_t)cb * 64 * 512;
  unsigned short* dst = (blockIdx.x < 256 ? KT : VT) + (size_t)cb * 32768;
  #pragma unroll
  for (int it = 0; it < 16; ++it) {
    int e = it * 2048 + tid * 8;
    int row = e >> 9, col = e & 511;
    *(uint4*)&Kc[row * 520 + col] = *(const uint4*)&src[row * 512 + col];
  }
  __syncthreads();
  #pragma unroll
  for (int it = 0; it < 16; ++it) {
    int e = it * 2048 + tid * 8;
    int dk = e >> 6, t0 = e & 63;
    uint4 o;
    unsigned short tv[8];
    #pragma unroll
    for (int u = 0; u < 8; ++u) tv[u] = Kc[(t0 + u) * 520 + dk];
    o.x = tv[0] | ((unsigned)tv[1] << 16);
    o.y = tv[2] | ((unsigned)tv[3] << 16);
    o.z = tv[4] | ((unsigned)tv[5] << 16);
    o.w = tv[6] | ((unsigned)tv[7] << 16);
    *(uint4*)&dst[e] = o;
  }
}

// ---------------- per-chunk Gram: A = strict_tril(beta_t * K K^T) f32, Ms = tril(Q K^T) bf16 ----------------
__global__ __launch_bounds__(256) void gram_kernel(
    const unsigned short* __restrict__ Qb, const unsigned short* __restrict__ Kb,
    const float* __restrict__ Beta, float* __restrict__ Abuf,
    unsigned short* __restrict__ Msb)
{
  int cb = blockIdx.x, tid = threadIdx.x, lane = tid & 63, w = tid >> 6;
  int lr = lane & 15, quad = lane >> 4;
  const unsigned short* kc = Kb + (size_t)cb * 64 * 512;
  const unsigned short* qc = Qb + (size_t)cb * 64 * 512;
  floatx4 accK[4], accQ[4];
  #pragma unroll
  for (int nt = 0; nt < 4; ++nt) { accK[nt] = (floatx4){0,0,0,0}; accQ[nt] = (floatx4){0,0,0,0}; }
  #pragma unroll
  for (int ks = 0; ks < 16; ++ks) {
    short8 ak = *(const short8*)&kc[(w * 16 + lr) * 512 + ks * 32 + quad * 8];
    short8 aq = *(const short8*)&qc[(w * 16 + lr) * 512 + ks * 32 + quad * 8];
    short8 bk[4];
    #pragma unroll
    for (int nt = 0; nt < 4; ++nt)
      bk[nt] = *(const short8*)&kc[(nt * 16 + lr) * 512 + ks * 32 + quad * 8];
    #pragma unroll
    for (int nt = 0; nt < 4; ++nt) {
      accK[nt] = __builtin_amdgcn_mfma_f32_16x16x32_bf16(ak, bk[nt], accK[nt], 0, 0, 0);
      accQ[nt] = __builtin_amdgcn_mfma_f32_16x16x32_bf16(aq, bk[nt], accQ[nt], 0, 0, 0);
    }
  }
  #pragma unroll
  for (int nt = 0; nt < 4; ++nt)
    #pragma unroll
    for (int r = 0; r < 4; ++r) {
      int t = w * 16 + quad * 4 + r;
      int j = nt * 16 + lr;
      float bt = Beta[cb * 64 + t];
      Abuf[(size_t)cb * 4096 + t * 64 + j] = (j < t) ? bt * accK[nt][r] : 0.f;
      Msb[(size_t)cb * 4096 + t * 64 + j]  = f2bf((j <= t) ? accQ[nt][r] : 0.f);
    }
}

// ---------------- Tinv = (I+A)^{-1}: 1 wave per block, lane owns column `lane` ----------------
// X stored transposed: XT[col][j] (stride 68 f32) so each lane reads only its own row -> b128.
__global__ __launch_bounds__(64) void tinv_kernel(
    const float* __restrict__ Abuf, const float* __restrict__ Beta,
    unsigned short* __restrict__ Tib)
{
  __shared__ float XT[64 * 68];
  int lane = threadIdx.x;
  int cb = blockIdx.x;
  float bl = Beta[cb * 64 + lane];
  const float* Ab = Abuf + (size_t)cb * 4096;
  unsigned short* To = Tib + (size_t)cb * 4096;
  float* Xr = XT + lane * 68;
  #pragma unroll
  for (int j = 0; j < 68; j += 4) *(float4*)&Xr[j] = (float4){0.f,0.f,0.f,0.f};
  for (int t = 0; t < 64; ++t) {
    const float* Ar = Ab + t * 64;
    float p0 = 0.f, p1 = 0.f, p2 = 0.f, p3 = 0.f;
    for (int jb = 0; jb < t; jb += 4) {           // A[t][j]=0 and X=0 for j>=t: over-read safe
      float4 xv = *(const float4*)&Xr[jb];
      float4 av = *(const float4*)&Ar[jb];
      p0 = fmaf(av.x, xv.x, p0); p1 = fmaf(av.y, xv.y, p1);
      p2 = fmaf(av.z, xv.z, p2); p3 = fmaf(av.w, xv.w, p3);
    }
    float y = ((lane == t) ? 1.f : 0.f) - (p0 + p1) - (p2 + p3);
    Xr[t] = y;
    To[t * 64 + lane] = f2bf(y * bl);
  }
}

// ---------------- Wneg = -Tinvbeta*K, Ubar = Tinvbeta*V; all-b128 in, LDS-staged coalesced out ----------------
__global__ __launch_bounds__(256) void wu_kernel(
    const unsigned short* __restrict__ Tib, const unsigned short* __restrict__ KT,
    const unsigned short* __restrict__ VT, unsigned short* __restrict__ Wneg,
    unsigned short* __restrict__ Ubar)
{
  __shared__ __align__(16) unsigned short WL[64 * 512];   // 64 KB
  __shared__ __align__(16) unsigned short UL[64 * 512];   // 64 KB
  int cb = blockIdx.x, tid = threadIdx.x, lane = tid & 63, w = tid >> 6;
  int lr = lane & 15, quad = lane >> 4;
  short8 af0 = *(const short8*)&Tib[(size_t)cb * 4096 + (w * 16 + lr) * 64 + quad * 8];
  short8 af1 = *(const short8*)&Tib[(size_t)cb * 4096 + (w * 16 + lr) * 64 + 32 + quad * 8];
  const unsigned short* ktc = KT + (size_t)cb * 32768 + lr * 64 + quad * 8;
  const unsigned short* vtc = VT + (size_t)cb * 32768 + lr * 64 + quad * 8;
  int tbase = w * 16 + quad * 4;
  #pragma unroll 4
  for (int nt = 0; nt < 32; ++nt) {
    short8 bk0 = *(const short8*)(ktc + nt * 1024);
    short8 bk1 = *(const short8*)(ktc + nt * 1024 + 32);
    short8 bv0 = *(const short8*)(vtc + nt * 1024);
    short8 bv1 = *(const short8*)(vtc + nt * 1024 + 32);
    floatx4 z = (floatx4){0.f,0.f,0.f,0.f};
    floatx4 aw = __builtin_amdgcn_mfma_f32_16x16x32_bf16(af0, bk0, z, 0, 0, 0);
    aw = __builtin_amdgcn_mfma_f32_16x16x32_bf16(af1, bk1, aw, 0, 0, 0);
    floatx4 au = __builtin_amdgcn_mfma_f32_16x16x32_bf16(af0, bv0, z, 0, 0, 0);
    au = __builtin_amdgcn_mfma_f32_16x16x32_bf16(af1, bv1, au, 0, 0, 0);
    int bi = nt * 2 + (lr >> 3);       // 16B-block index of dd = nt*16+lr
    int lo = lr & 7;
    #pragma unroll
    for (int r = 0; r < 4; ++r) {
      int tt = tbase + r;
      int bis = bi ^ (tt & 7);         // XOR swizzle vs row
      WL[tt * 512 + bis * 8 + lo] = f2bf(-aw[r]);
      UL[tt * 512 + bis * 8 + lo] = f2bf(au[r]);
    }
  }
  __syncthreads();
  unsigned short* wd = Wneg + (size_t)cb * 32768;
  unsigned short* ud = Ubar + (size_t)cb * 32768;
  #pragma unroll
  for (int it = 0; it < 16; ++it) {
    int e = it * 2048 + tid * 8;
    int row = e >> 9, col = e & 511;
    int bis = (col >> 3) ^ (row & 7);
    *(uint4*)&wd[e] = *(const uint4*)&WL[row * 512 + bis * 8];
    *(uint4*)&ud[e] = *(const uint4*)&UL[row * 512 + bis * 8];
  }
}

// ---------------- sequential chunk scan with rolling register prefetch ----------------
// per chunk: U = Ubar + Wneg*S^T ; O = Q*S^T + Ms*U ; S += U^T*K. 2 barriers/chunk.
__global__ __launch_bounds__(256, 1) void seq_kernel(
    const unsigned short* __restrict__ Wneg, const unsigned short* __restrict__ Qb,
    const unsigned short* __restrict__ Ubar, const unsigned short* __restrict__ Msb,
    const unsigned short* __restrict__ KT, unsigned short* __restrict__ Ob)
{
  __shared__ __align__(16) unsigned short Sb[16 * 520];
  __shared__ __align__(16) unsigned short Ut[16 * 72];
  int blk = blockIdx.x;
  int b = blk >> 5, vs = blk & 31;
  int vg0 = vs * 16;
  int tid = threadIdx.x, lane = tid & 63, w = tid >> 6;
  int lr = lane & 15, quad = lane >> 4;

  floatx4 sacc[8];
  #pragma unroll
  for (int nt = 0; nt < 8; ++nt) sacc[nt] = (floatx4){0.f,0.f,0.f,0.f};

  short8 wn[16], qf[16], kt[16], ms[2];
  unsigned short ub[4];

  auto LD_WQ = [&](int cb) {
    const unsigned short* wr = Wneg + ((size_t)cb * 64 + w * 16 + lr) * 512 + quad * 8;
    const unsigned short* qr = Qb   + ((size_t)cb * 64 + w * 16 + lr) * 512 + quad * 8;
    #pragma unroll
    for (int ks = 0; ks < 16; ++ks) {
      wn[ks] = *(const short8*)(wr + ks * 32);
      qf[ks] = *(const short8*)(qr + ks * 32);
    }
  };
  auto LD_KM = [&](int cb) {
    const unsigned short* kr = KT + (size_t)cb * 32768 + (w * 128 + lr) * 64 + quad * 8;
    #pragma unroll
    for (int nt = 0; nt < 8; ++nt) {
      kt[nt * 2 + 0] = *(const short8*)(kr + nt * 1024);
      kt[nt * 2 + 1] = *(const short8*)(kr + nt * 1024 + 32);
    }
    const unsigned short* mr = Msb + (size_t)cb * 4096 + (w * 16 + lr) * 64 + quad * 8;
    ms[0] = *(const short8*)(mr);
    ms[1] = *(const short8*)(mr + 32);
  };
  auto LD_UB = [&](int cb) {
    const unsigned short* ur = Ubar + ((size_t)cb * 64 + w * 16 + quad * 4) * 512 + vg0 + lr;
    #pragma unroll
    for (int r = 0; r < 4; ++r) ub[r] = ur[r * 512];
  };

  int cb0 = b * NCHB;
  LD_WQ(cb0); LD_KM(cb0); LD_UB(cb0);

  for (int ch = 0; ch < NCHB; ++ch) {
    int cb = cb0 + ch;
    int cbn = cb0 + (ch + 1 < NCHB ? ch + 1 : ch);
    // phase 0: stage S^T (bf16) into LDS
    #pragma unroll
    for (int nt = 0; nt < 8; ++nt)
      #pragma unroll
      for (int r = 0; r < 4; ++r)
        Sb[(quad * 4 + r) * 520 + w * 128 + nt * 16 + lr] = f2bf(sacc[nt][r]);
    __syncthreads();
    // phase 1: U-GEMM and Q*S^T interleaved (4 independent accumulator chains)
    floatx4 du0, du1, do0, do1;
    #pragma unroll
    for (int r = 0; r < 4; ++r) du0[r] = bf2f(ub[r]);
    du1 = (floatx4){0.f,0.f,0.f,0.f};
    do0 = (floatx4){0.f,0.f,0.f,0.f};
    do1 = (floatx4){0.f,0.f,0.f,0.f};
    #pragma unroll
    for (int ks = 0; ks < 16; ++ks) {
      short8 sb = *(const short8*)&Sb[lr * 520 + ks * 32 + quad * 8];
      if (ks & 1) {
        du1 = __builtin_amdgcn_mfma_f32_16x16x32_bf16(wn[ks], sb, du1, 0, 0, 0);
        do1 = __builtin_amdgcn_mfma_f32_16x16x32_bf16(qf[ks], sb, do1, 0, 0, 0);
      } else {
        du0 = __builtin_amdgcn_mfma_f32_16x16x32_bf16(wn[ks], sb, du0, 0, 0, 0);
        do0 = __builtin_amdgcn_mfma_f32_16x16x32_bf16(qf[ks], sb, do0, 0, 0, 0);
      }
    }
    #pragma unroll
    for (int r = 0; r < 4; ++r)
      Ut[lr * 72 + w * 16 + quad * 4 + r] = f2bf(du0[r] + du1[r]);
    LD_WQ(cbn);                      // prefetch: wn/qf dead
    LD_UB(cbn);                      // prefetch: ub consumed into du0
    __syncthreads();
    // phase 2: Ms*U into O, S += U^T*K
    short8 a2_0 = *(const short8*)&Ut[lr * 72 + quad * 8];
    short8 a2_1 = *(const short8*)&Ut[lr * 72 + 32 + quad * 8];
    do0 = __builtin_amdgcn_mfma_f32_16x16x32_bf16(ms[0], a2_0, do0, 0, 0, 0);
    do1 = __builtin_amdgcn_mfma_f32_16x16x32_bf16(ms[1], a2_1, do1, 0, 0, 0);
    #pragma unroll
    for (int nt = 0; nt < 8; ++nt) {
      sacc[nt] = __builtin_amdgcn_mfma_f32_16x16x32_bf16(a2_0, kt[nt * 2 + 0], sacc[nt], 0, 0, 0);
      sacc[nt] = __builtin_amdgcn_mfma_f32_16x16x32_bf16(a2_1, kt[nt * 2 + 1], sacc[nt], 0, 0, 0);
    }
    {
      unsigned short* ob = Ob + ((size_t)cb * 64 + w * 16 + quad * 4) * 512 + vg0 + lr;
      #pragma unroll
      for (int r = 0; r < 4; ++r) ob[r * 512] = f2bf(do0[r] + do1[r]);
    }
    LD_KM(cbn);                      // prefetch: kt/ms dead
    // no barrier needed: next phase-0 writes Sb (already unread since last sync),
    // next phase-1's Ut write is gated by next __syncthreads()
  }
}

extern "C" void kernel_launch(void* const* d_in, const int* in_sizes, int n_in,
                              void* d_out, int out_size, void* d_ws, size_t ws_size,
                              hipStream_t stream) {
  const float* x     = (const float*)d_in[0];
  const float* Wq    = (const float*)d_in[1];
  const float* bq    = (const float*)d_in[2];
  const float* Wk    = (const float*)d_in[3];
  const float* bk    = (const float*)d_in[4];
  const float* Wv    = (const float*)d_in[5];
  const float* bv    = (const float*)d_in[6];
  const float* Wbeta = (const float*)d_in[7];
  const float* bbeta = (const float*)d_in[8];
  const float* Wo    = (const float*)d_in[9];
  const float* bo    = (const float*)d_in[10];

  const size_t NE = (size_t)M_ROWS * D;   // 8,388,608
  const size_t DD = (size_t)D * D;
  unsigned short* Qb  = (unsigned short*)d_ws;
  unsigned short* Kb  = Qb + NE;          // later: Ubar
  unsigned short* Vb  = Kb + NE;          // later: O
  unsigned short* Xb  = Vb + NE;          // x bf16; later: Wneg
  unsigned short* Wqb = Xb + NE;
  unsigned short* Wkb = Wqb + DD;
  unsigned short* Wvb = Wkb + DD;
  unsigned short* Wob = Wvb + DD;
  float* Beta = (float*)(Wob + DD);                        // 16384 f32
  unsigned short* KT  = (unsigned short*)(Beta + M_ROWS);  // NE shorts
  float* Abuf = (float*)(KT + NE);                         // 256*4096 f32
  unsigned short* Msb = (unsigned short*)(Abuf + (size_t)NCHUNK * 4096);
  unsigned short* Tib = Msb + (size_t)NCHUNK * 4096;
  unsigned short* VT  = Tib + (size_t)NCHUNK * 4096;       // NE shorts; total ~106 MB

  cast_kernel<<<(int)(NE / 2048), 256, 0, stream>>>(x, Xb, (int)NE);
  cast_kernel<<<(int)(DD / 2048), 256, 0, stream>>>(Wq, Wqb, (int)DD);
  cast_kernel<<<(int)(DD / 2048), 256, 0, stream>>>(Wk, Wkb, (int)DD);
  cast_kernel<<<(int)(DD / 2048), 256, 0, stream>>>(Wv, Wvb, (int)DD);
  cast_kernel<<<(int)(DD / 2048), 256, 0, stream>>>(Wo, Wob, (int)DD);

  dim3 gg(D / BN, M_ROWS / BM);  // (4, 128)
  gemm_nt<true><<<gg, 256, 0, stream>>>(Xb, Wqb, bq, Qb, M_ROWS, D, D);
  gemm_nt<true><<<gg, 256, 0, stream>>>(Xb, Wkb, bk, Kb, M_ROWS, D, D);
  gemm_nt<true><<<gg, 256, 0, stream>>>(Xb, Wvb, bv, Vb, M_ROWS, D, D);

  norm_beta_kernel<<<M_ROWS / 4, 256, 0, stream>>>(Kb, Wbeta, bbeta, Beta);

  transpose_kv<<<2 * NCHUNK, 256, 0, stream>>>(Kb, Vb, KT, VT);
  gram_kernel<<<NCHUNK, 256, 0, stream>>>(Qb, Kb, Beta, Abuf, Msb);
  tinv_kernel<<<NCHUNK, 64, 0, stream>>>(Abuf, Beta, Tib);
  wu_kernel<<<NCHUNK, 256, 0, stream>>>(Tib, KT, VT, /*Wneg=*/Xb, /*Ubar=*/Kb);

  seq_kernel<<<NCHUNK, 256, 0, stream>>>(/*Wneg=*/Xb, Qb, /*Ubar=*/Kb, Msb, KT, /*O=*/Vb);

  gemm_nt<false><<<gg, 256, 0, stream>>>(Vb, Wob, bo, (float*)d_out, M_ROWS, D, D);
}